// Round 5
// baseline (176.903 us; speedup 1.0000x reference)
//
#include <hip/hip_runtime.h>
#include <hip/hip_fp16.h>

#define CCH 48         // channels
#define NPB 128        // nodes per bucket (1<<7); requires N <= 128*1024
#define NPB_SH 7
#define MAXNB 1024     // max buckets the LDS histograms support
#define SCAT_EPB 16384 // edges per scatter block (256 thr x 64, two-pass)

// --- k1: two-pass block-aggregated scatter into fixed-capacity bucket regions ---
// pass 1: LDS bucket histograms (col + row) over this block's 16384 edges
// reserve: one global atomic per (block,bucket); reservations line-padded,
//          pads filled with sentinels (-1 / 0xFF) so every line has one owner
// pass 2: re-read edges (L2-hot) and scatter records to the reserved ranges
// col record: row | (col&127)<<24 (4B) -> pairs[]   row record: row&127 (1B) -> rbytes[]
__global__ void __launch_bounds__(256) bucket_scatter(const int* __restrict__ row,
                                                      const int* __restrict__ col,
                                                      int* __restrict__ colCur,
                                                      int* __restrict__ rowCur,
                                                      int* __restrict__ pairs,
                                                      unsigned char* __restrict__ rbytes,
                                                      int NB, int E, int CAPC, int CAPR) {
    __shared__ int sc[MAXNB], sr[MAXNB];
    int tid = threadIdx.x;
    for (int i = tid; i < NB; i += 256) { sc[i] = 0; sr[i] = 0; }
    __syncthreads();
    int base = blockIdx.x * SCAT_EPB;
    bool full = (base + SCAT_EPB <= E);
    // ---- pass 1: count ----
    if (full) {
#pragma unroll 4
        for (int k = 0; k < 16; ++k) {
            int idx = base + (k * 256 + tid) * 4;
            int4 c = *reinterpret_cast<const int4*>(col + idx);
            int4 r = *reinterpret_cast<const int4*>(row + idx);
            atomicAdd(&sc[c.x >> NPB_SH], 1); atomicAdd(&sc[c.y >> NPB_SH], 1);
            atomicAdd(&sc[c.z >> NPB_SH], 1); atomicAdd(&sc[c.w >> NPB_SH], 1);
            atomicAdd(&sr[r.x >> NPB_SH], 1); atomicAdd(&sr[r.y >> NPB_SH], 1);
            atomicAdd(&sr[r.z >> NPB_SH], 1); atomicAdd(&sr[r.w >> NPB_SH], 1);
        }
    } else {
        for (int e = base + tid; e < E; e += 256) {
            atomicAdd(&sc[col[e] >> NPB_SH], 1);
            atomicAdd(&sr[row[e] >> NPB_SH], 1);
        }
    }
    __syncthreads();
    // ---- reserve: LDS slot becomes absolute write cursor ----
    for (int i = tid; i < NB; i += 256) {
        int nc = sc[i];
        if (nc) {
            int padded = (nc + 15) & ~15;  // 64B-line multiple (ints)
            int b0 = i * CAPC + atomicAdd(colCur + i, padded);
            sc[i] = b0;
            for (int j = nc; j < padded; ++j) pairs[b0 + j] = -1;
        }
        int nr = sr[i];
        if (nr) {
            int padded = (nr + 31) & ~31;  // 32B-sector multiple (bytes)
            int b0 = i * CAPR + atomicAdd(rowCur + i, padded);
            sr[i] = b0;
            for (int j = nr; j < padded; ++j) rbytes[b0 + j] = 0xFF;
        }
    }
    __syncthreads();
    // ---- pass 2: scatter (re-read, L2-hot) ----
    if (full) {
#pragma unroll 4
        for (int k = 0; k < 16; ++k) {
            int idx = base + (k * 256 + tid) * 4;
            int4 c = *reinterpret_cast<const int4*>(col + idx);
            int4 r = *reinterpret_cast<const int4*>(row + idx);
            int p, q;
            p = atomicAdd(&sc[c.x >> NPB_SH], 1); pairs[p] = r.x | ((c.x & 127) << 24);
            q = atomicAdd(&sr[r.x >> NPB_SH], 1); rbytes[q] = (unsigned char)(r.x & 127);
            p = atomicAdd(&sc[c.y >> NPB_SH], 1); pairs[p] = r.y | ((c.y & 127) << 24);
            q = atomicAdd(&sr[r.y >> NPB_SH], 1); rbytes[q] = (unsigned char)(r.y & 127);
            p = atomicAdd(&sc[c.z >> NPB_SH], 1); pairs[p] = r.z | ((c.z & 127) << 24);
            q = atomicAdd(&sr[r.z >> NPB_SH], 1); rbytes[q] = (unsigned char)(r.z & 127);
            p = atomicAdd(&sc[c.w >> NPB_SH], 1); pairs[p] = r.w | ((c.w & 127) << 24);
            q = atomicAdd(&sr[r.w >> NPB_SH], 1); rbytes[q] = (unsigned char)(r.w & 127);
        }
    } else {
        for (int e = base + tid; e < E; e += 256) {
            int cc = col[e], rr = row[e];
            int p = atomicAdd(&sc[cc >> NPB_SH], 1);
            pairs[p] = rr | ((cc & 127) << 24);
            int q = atomicAdd(&sr[rr >> NPB_SH], 1);
            rbytes[q] = (unsigned char)(rr & 127);
        }
    }
}

// --- k2: per-bucket CSR build (in-place via LDS stage, sentinel-skip) +
//         row-degree -> dis + fused fp16 scale-convert of the bucket's rows ---
__global__ void __launch_bounds__(256) csr_deg_conv(int* __restrict__ pairs,
                                                    const int* __restrict__ colCur,
                                                    const unsigned char* __restrict__ rbytes,
                                                    const int* __restrict__ rowCur,
                                                    const float* __restrict__ label,
                                                    int2* __restrict__ ptr2,
                                                    float* __restrict__ dis,
                                                    __half* __restrict__ lab16,
                                                    int N, int CAPC, int CAPR) {
    extern __shared__ int stage[];  // CAPC ints
    __shared__ int cnt[256], scn[NPB];
    __shared__ float ds[NPB];
    int b = blockIdx.x, tid = threadIdx.x;
    int begc = b * CAPC;
    int cnum = colCur[b];  // padded count (multiple of 16)
    cnt[tid] = 0;
    __syncthreads();
    int nq = cnum >> 2;  // exact: cnum multiple of 16
    for (int q = tid; q < nq; q += 256) {
        int4 pk = *reinterpret_cast<const int4*>(pairs + begc + q * 4);
        *reinterpret_cast<int4*>(stage + q * 4) = pk;
        if (pk.x >= 0) atomicAdd(&cnt[((unsigned)pk.x) >> 24], 1);
        if (pk.y >= 0) atomicAdd(&cnt[((unsigned)pk.y) >> 24], 1);
        if (pk.z >= 0) atomicAdd(&cnt[((unsigned)pk.z) >> 24], 1);
        if (pk.w >= 0) atomicAdd(&cnt[((unsigned)pk.w) >> 24], 1);
    }
    __syncthreads();
    int v = (tid < NPB) ? cnt[tid] : 0;
    if (tid < NPB) scn[tid] = v;
    __syncthreads();
    for (int off = 1; off < NPB; off <<= 1) {
        int t = (tid >= off && tid < NPB) ? scn[tid - off] : 0;
        __syncthreads();
        if (tid < NPB) scn[tid] += t;
        __syncthreads();
    }
    int n0 = b << NPB_SH;
    if (tid < NPB) {
        int start = begc + scn[tid] - v;  // exclusive prefix, absolute
        int n = n0 + tid;
        if (n < N) ptr2[n] = make_int2(start, start + v);
        cnt[tid] = start;  // absolute cursor
    }
    __syncthreads();
    // scatter src ids back over the same region (stage holds originals)
    for (int i = tid; i < cnum; i += 256) {
        int pk = stage[i];
        if (pk >= 0) {
            int p = atomicAdd(&cnt[((unsigned)pk) >> 24], 1);
            pairs[p] = pk & 0x00FFFFFF;
        }
    }
    // --- row side: degree histogram -> dis (slot 255 catches sentinels) ---
    __syncthreads();
    cnt[tid] = 0;
    __syncthreads();
    int begr = b * CAPR;
    int rnum = rowCur[b];  // padded count (multiple of 32)
    int nq4 = rnum >> 2;   // exact
    for (int q = tid; q < nq4; q += 256) {
        uchar4 u = *reinterpret_cast<const uchar4*>(rbytes + begr + q * 4);
        atomicAdd(&cnt[u.x], 1);
        atomicAdd(&cnt[u.y], 1);
        atomicAdd(&cnt[u.z], 1);
        atomicAdd(&cnt[u.w], 1);
    }
    __syncthreads();
    if (tid < NPB) {
        float w = rsqrtf((float)cnt[tid] + 1.0f);
        ds[tid] = w;
        if (n0 + tid < N) dis[n0 + tid] = w;
    }
    __syncthreads();
    // --- fused convert: lab16[n,c] = (half)(dis[n]*label[n,c]), 2 thr/row ---
    int rr = tid >> 1, hf = tid & 1;
    int n = n0 + rr;
    if (n < N) {
        float w = ds[rr];
        const float4* src4 = reinterpret_cast<const float4*>(label + (size_t)n * CCH + hf * 24);
        uint4* dst = reinterpret_cast<uint4*>(lab16 + (size_t)n * CCH + hf * 24);
#pragma unroll
        for (int k = 0; k < 3; ++k) {
            float4 a = src4[2 * k];
            float4 cc = src4[2 * k + 1];
            union { __half2 h[4]; uint4 u; } pkk;
            pkk.h[0] = __floats2half2_rn(w * a.x, w * a.y);
            pkk.h[1] = __floats2half2_rn(w * a.z, w * a.w);
            pkk.h[2] = __floats2half2_rn(w * cc.x, w * cc.y);
            pkk.h[3] = __floats2half2_rn(w * cc.z, w * cc.w);
            dst[k] = pkk.u;
        }
    }
}

// --- k3: pull-gather over fp16 pre-scaled rows; 8 lanes/node, 6 ch/lane, 4-edge unroll ---
// out[n,c] = dis[n] * ( sum_{e: col=n} lab16[src,c] + lab16[n,c] )
__global__ void __launch_bounds__(256) gather16(const __half* __restrict__ lab16,
                                                const int2* __restrict__ ptr2,
                                                const int* __restrict__ srcA,
                                                const float* __restrict__ dis,
                                                float* __restrict__ out, int N) {
    int t = blockIdx.x * blockDim.x + threadIdx.x;
    int n = t >> 3;
    if (n >= N) return;
    int c0 = (t & 7) * 6;
    int2 be = ptr2[n];
    float a0 = 0.f, a1 = 0.f, a2 = 0.f, a3 = 0.f, a4 = 0.f, a5 = 0.f;
    int i = be.x, end = be.y;
    for (; i + 4 <= end; i += 4) {
        int s0 = srcA[i], s1 = srcA[i + 1], s2 = srcA[i + 2], s3 = srcA[i + 3];
        const __half2* p0 = reinterpret_cast<const __half2*>(lab16 + (size_t)s0 * CCH + c0);
        const __half2* p1 = reinterpret_cast<const __half2*>(lab16 + (size_t)s1 * CCH + c0);
        const __half2* p2 = reinterpret_cast<const __half2*>(lab16 + (size_t)s2 * CCH + c0);
        const __half2* p3 = reinterpret_cast<const __half2*>(lab16 + (size_t)s3 * CCH + c0);
        __half2 x0 = p0[0], x1 = p0[1], x2 = p0[2];
        __half2 y0 = p1[0], y1 = p1[1], y2 = p1[2];
        __half2 z0 = p2[0], z1 = p2[1], z2 = p2[2];
        __half2 w0 = p3[0], w1 = p3[1], w2 = p3[2];
        float2 f;
        f = __half22float2(x0); a0 += f.x; a1 += f.y;
        f = __half22float2(x1); a2 += f.x; a3 += f.y;
        f = __half22float2(x2); a4 += f.x; a5 += f.y;
        f = __half22float2(y0); a0 += f.x; a1 += f.y;
        f = __half22float2(y1); a2 += f.x; a3 += f.y;
        f = __half22float2(y2); a4 += f.x; a5 += f.y;
        f = __half22float2(z0); a0 += f.x; a1 += f.y;
        f = __half22float2(z1); a2 += f.x; a3 += f.y;
        f = __half22float2(z2); a4 += f.x; a5 += f.y;
        f = __half22float2(w0); a0 += f.x; a1 += f.y;
        f = __half22float2(w1); a2 += f.x; a3 += f.y;
        f = __half22float2(w2); a4 += f.x; a5 += f.y;
    }
    for (; i < end; ++i) {
        int s0 = srcA[i];
        const __half2* p0 = reinterpret_cast<const __half2*>(lab16 + (size_t)s0 * CCH + c0);
        __half2 x0 = p0[0], x1 = p0[1], x2 = p0[2];
        float2 f;
        f = __half22float2(x0); a0 += f.x; a1 += f.y;
        f = __half22float2(x1); a2 += f.x; a3 += f.y;
        f = __half22float2(x2); a4 += f.x; a5 += f.y;
    }
    // self loop: lab16[n] is already dis[n]*label[n]
    {
        const __half2* ps = reinterpret_cast<const __half2*>(lab16 + (size_t)n * CCH + c0);
        __half2 x0 = ps[0], x1 = ps[1], x2 = ps[2];
        float2 f;
        f = __half22float2(x0); a0 += f.x; a1 += f.y;
        f = __half22float2(x1); a2 += f.x; a3 += f.y;
        f = __half22float2(x2); a4 += f.x; a5 += f.y;
    }
    float dn = dis[n];
    float* o = out + (size_t)n * CCH + c0;
    o[0] = dn * a0; o[1] = dn * a1; o[2] = dn * a2;
    o[3] = dn * a3; o[4] = dn * a4; o[5] = dn * a5;
}

extern "C" void kernel_launch(void* const* d_in, const int* in_sizes, int n_in,
                              void* d_out, int out_size, void* d_ws, size_t ws_size,
                              hipStream_t stream) {
    const float* label = (const float*)d_in[0];  // fp32 (N,48)
    const int* ei = (const int*)d_in[1];         // int32, (2,E) flat

    const int NC = in_sizes[0];  // N * 48
    const int N  = NC / CCH;
    const int E  = in_sizes[1] / 2;
    const int* row = ei;
    const int* col = ei + E;

    const int NB = (N + NPB - 1) >> NPB_SH;             // 782 at N=100000
    const int sblocks = (E + SCAT_EPB - 1) / SCAT_EPB;  // 98 at E=1.6M
    const int avg = (E + NB - 1) / NB;                  // ~2047
    // bucket totals: actual + per-fragment pad bound + randomness slack
    const int CAPC = (avg + 15 * sblocks + 512 + 15) & ~15;   // ints, ~4032
    const int CAPR = (avg + 31 * sblocks + 512 + 63) & ~63;   // bytes, ~5632

    // ws layout (16B-aligned sections):
    // [pairs NB*CAPC int] [colCur NB][rowCur NB] [ptr2 N int2] [dis N f32] [pad]
    // [rbytes NB*CAPR bytes] [lab16 N*48 half]
    int* pairs = (int*)d_ws;
    int* colCur = pairs + (size_t)NB * CAPC;
    int* rowCur = colCur + NB;
    int2* ptr2 = (int2*)(rowCur + NB);
    float* dis = (float*)(ptr2 + N);
    size_t rb_off = (((size_t)(dis + N) - (size_t)d_ws) + 63) & ~(size_t)63;
    unsigned char* rbytes = (unsigned char*)d_ws + rb_off;
    __half* lab16 = (__half*)(rbytes + (size_t)NB * CAPR);

    // zero the two cursor arrays (~6 KB)
    hipMemsetAsync(colCur, 0, (size_t)(2 * NB) * sizeof(int), stream);

    bucket_scatter<<<sblocks, 256, 0, stream>>>(row, col, colCur, rowCur,
                                                pairs, rbytes, NB, E, CAPC, CAPR);
    csr_deg_conv<<<NB, 256, (size_t)CAPC * sizeof(int), stream>>>(
        pairs, colCur, rbytes, rowCur, label, ptr2, dis, lab16, N, CAPC, CAPR);
    gather16<<<(N * 8 + 255) / 256, 256, 0, stream>>>(lab16, ptr2, pairs /*srcA in-place*/,
                                                      dis, (float*)d_out, N);
}